// Round 13
// baseline (243.336 us; speedup 1.0000x reference)
//
#include <hip/hip_runtime.h>
#include <hip/hip_bf16.h>

#define E_NUM 64
#define IN_SZ 512
#define OUT_SZ 512
#define N_TOK 131072
#define CAP 3072

#define BM 128
#define BN 256
#define BK 32
#define THREADS 512
#define RT_MAX 24   // CAP/BM
#define CT_NUM 2    // OUT/BN
#define JT 16       // IN_SZ/BK
#define NWG (E_NUM * RT_MAX * CT_NUM)
#define ATOT ((long)N_TOK * IN_SZ)

typedef __attribute__((ext_vector_type(8))) short short8;
typedef __attribute__((ext_vector_type(4))) float f32x4;

__device__ inline unsigned short f2bf(float f) {
    unsigned int u = __float_as_uint(f);
    unsigned int r = (u + 0x7FFF + ((u >> 16) & 1)) >> 16;
    return (unsigned short)r;
}

#define GLOAD_LDS16(g, l)                                                     \
    __builtin_amdgcn_global_load_lds(                                         \
        (const __attribute__((address_space(1))) void*)(g),                   \
        (__attribute__((address_space(3))) void*)(l), 16, 0, 0)

// ---------------- kernel 1: exclusive prefix sum of expert sizes ----------
__global__ void offsets_kernel(const int* __restrict__ sizes, int* __restrict__ offs) {
    int e = threadIdx.x;
    int s = 0;
    for (int i = 0; i < e; ++i) s += sizes[i];
    offs[e] = s;
}

// ---------------- kernel 2: W [E][K][N] f32 -> WT [E][N][K] bf16 ----------
__global__ __launch_bounds__(256) void prep_wt(const float* __restrict__ W,
                                               unsigned short* __restrict__ WT) {
    __shared__ float t[32][33];
    int k0 = blockIdx.x * 32, n0 = blockIdx.y * 32, e = blockIdx.z;
    const float* We = W + (size_t)e * IN_SZ * OUT_SZ;
    int tid = threadIdx.x;
    int r = tid >> 3, c4 = (tid & 7) * 4;
    float4 v = *(const float4*)(We + (size_t)(k0 + r) * OUT_SZ + n0 + c4);
    t[r][c4 + 0] = v.x; t[r][c4 + 1] = v.y; t[r][c4 + 2] = v.z; t[r][c4 + 3] = v.w;
    __syncthreads();
    ushort4 o;
    o.x = f2bf(t[c4 + 0][r]);
    o.y = f2bf(t[c4 + 1][r]);
    o.z = f2bf(t[c4 + 2][r]);
    o.w = f2bf(t[c4 + 3][r]);
    unsigned short* O = WT + (size_t)e * IN_SZ * OUT_SZ + (size_t)(n0 + r) * IN_SZ + k0 + c4;
    *(ushort4*)O = o;
}

// ---------------- kernel 2b: A f32 -> bf16 (streaming) --------------------
__global__ __launch_bounds__(256) void prep_a(const float* __restrict__ A,
                                              unsigned short* __restrict__ Abf) {
    long i = ((long)blockIdx.x * 256 + threadIdx.x) * 8;
    long stride = (long)gridDim.x * 256 * 8;
    for (; i < ATOT; i += stride) {
        float4 v0 = *(const float4*)(A + i);
        float4 v1 = *(const float4*)(A + i + 4);
        short8 o;
        o[0] = (short)f2bf(v0.x); o[1] = (short)f2bf(v0.y);
        o[2] = (short)f2bf(v0.z); o[3] = (short)f2bf(v0.w);
        o[4] = (short)f2bf(v1.x); o[5] = (short)f2bf(v1.y);
        o[6] = (short)f2bf(v1.z); o[7] = (short)f2bf(v1.w);
        *(short8*)(Abf + i) = o;
    }
}

// ---------------- kernel 3 (fast): m97-isomorphic all-bf16 DMA GEMM -------
// Both operands bf16, both staged via global_load_lds (1 A + 2 B calls/iter),
// 8 ds_read_b128 + 16 MFMA per wave per iter, ONE plain __syncthreads.
// LDS 48 KB -> 3 blocks/CU = 24 waves/CU. No reg staging, no in-loop cvt.
// Swizzle (verified 0-conflict): 16B-slot ^= (row>>1)&3 within 64B k-row,
// applied on the pre-swizzled GLOBAL source (linear LDS dest) + same XOR
// on ds_read (involution, rule #21).
__global__ __launch_bounds__(THREADS, 4) void gemm_moe_dma(
    const unsigned short* __restrict__ Abf, const int* __restrict__ sizes,
    const unsigned short* __restrict__ WT, const int* __restrict__ offs,
    float* __restrict__ out)
{
    // bijective XCD swizzle: 3072 blocks, 384 per XCD chunk
    int b0 = blockIdx.x;
    int wg = (b0 & 7) * (NWG / 8) + (b0 >> 3);
    int ct = wg & (CT_NUM - 1);
    int rt = (wg >> 1) % RT_MAX;
    int e  = wg / (RT_MAX * CT_NUM);

    int size_e = sizes[e];
    int rows0 = rt * BM;
    if (rows0 >= size_e) return;
    int off_e = offs[e];
    int rows_rem = size_e - rows0;                      // >= 1
    int maxr = (rows_rem < BM ? rows_rem : BM) - 1;

    __shared__ unsigned short lsA[2][BM * BK];   // 2 x 8 KB
    __shared__ unsigned short lsB[2][BN * BK];   // 2 x 16 KB -> 48 KB total

    int tid = threadIdx.x, l = tid & 63, w = tid >> 6;   // w in 0..7
    const char* Ae  = (const char*)(Abf + (size_t)(off_e + rows0) * IN_SZ);
    const char* WTe = (const char*)(WT + (size_t)e * IN_SZ * OUT_SZ);

    // A: one call stages 8 KB. HW dest = base(w*1024B) + lane*16 ->
    // row = w*16 + (l>>2), slot = l&3; source col = (slot ^ ((row>>1)&3))*16
    int arow = w * 16 + (l >> 2);
    int gar = arow <= maxr ? arow : maxr;
    const char* gA = Ae + (size_t)gar * (IN_SZ * 2)
                   + (((l & 3) ^ ((arow >> 1) & 3)) * 16);
    // B: chunks c = w*2+i; row n = c*16 + (l>>2); same swizzle form
    const char* gB[2];
    #pragma unroll
    for (int i = 0; i < 2; ++i) {
        int c = w * 2 + i;
        int n = c * 16 + (l >> 2);
        int csrc = ((l & 3) * 16) ^ (((l >> 3) & 3) << 4);
        gB[i] = WTe + (size_t)(ct * BN + n) * (IN_SZ * 2) + csrc;
    }

    auto stageA = [&](int buf, int kt) {
        GLOAD_LDS16(gA + kt * 64, &lsA[buf][w * 512]);
    };
    auto stageB = [&](int buf, int kt) {
        #pragma unroll
        for (int i = 0; i < 2; ++i)
            GLOAD_LDS16(gB[i] + kt * 64, &lsB[buf][(w * 2 + i) * 512]);
    };

    int wm = (w >> 2) * 64, wn = (w & 3) * 64;   // 2x4 grid of 64x64
    int lrow = l & 15;
    int cb = ((l >> 4) * 16) ^ (((l >> 1) & 3) << 4);

    f32x4 acc[4][4] = {};

    // ---- prologue: tile 0 staged ----
    stageA(0, 0); stageB(0, 0);
    __syncthreads();

    // ---- main loop: one barrier per iteration, no asm pins ----
    #pragma unroll
    for (int j = 0; j < JT; ++j) {
        int cur = j & 1;
        if (j + 1 < JT) {
            stageA(cur ^ 1, j + 1);
            stageB(cur ^ 1, j + 1);
        }
        {
            const char* pA = (const char*)&lsA[cur][0];
            const char* pB = (const char*)&lsB[cur][0];
            short8 af[4];
            #pragma unroll
            for (int m = 0; m < 4; ++m)
                af[m] = *(const short8*)(pA + (wm + m * 16 + lrow) * 64 + cb);
            __builtin_amdgcn_s_setprio(1);
            #pragma unroll
            for (int n = 0; n < 4; ++n) {
                short8 bf = *(const short8*)(pB + (wn + n * 16 + lrow) * 64 + cb);
                #pragma unroll
                for (int m = 0; m < 4; ++m)
                    acc[m][n] = __builtin_amdgcn_mfma_f32_16x16x32_bf16(
                        af[m], bf, acc[m][n], 0, 0, 0);
            }
            __builtin_amdgcn_s_setprio(0);
        }
        if (j < JT - 1)
            __syncthreads();
    }

    // epilogue: C/D layout col = lane&15, row = (lane>>4)*4 + reg
    float* outb = out + (size_t)(off_e + rows0) * OUT_SZ + ct * BN + wn;
    #pragma unroll
    for (int m = 0; m < 4; ++m) {
        #pragma unroll
        for (int j = 0; j < 4; ++j) {
            int rl = wm + m * 16 + (l >> 4) * 4 + j;
            if (rl < rows_rem) {
                float* po = outb + (size_t)rl * OUT_SZ + lrow;
                #pragma unroll
                for (int n = 0; n < 4; ++n)
                    po[n * 16] = acc[m][n][j];
            }
        }
    }
}

// ---------------- kernel 3 (fallback): R12 reg-staged fp32-A GEMM ---------
__global__ __launch_bounds__(THREADS, 4) void gemm_moe_reg(
    const float* __restrict__ A, const int* __restrict__ sizes,
    const unsigned short* __restrict__ WT, const int* __restrict__ offs,
    float* __restrict__ out)
{
    int b0 = blockIdx.x;
    int wg = (b0 & 7) * (NWG / 8) + (b0 >> 3);
    int ct = wg & (CT_NUM - 1);
    int rt = (wg >> 1) % RT_MAX;
    int e  = wg / (RT_MAX * CT_NUM);

    int size_e = sizes[e];
    int rows0 = rt * BM;
    if (rows0 >= size_e) return;
    int off_e = offs[e];
    int rows_rem = size_e - rows0;
    int maxr = (rows_rem < BM ? rows_rem : BM) - 1;

    __shared__ unsigned short lsA[2][BM * BK];
    __shared__ unsigned short lsB[2][BN * BK];

    int tid = threadIdx.x, l = tid & 63, w = tid >> 6;
    const char* WTe = (const char*)(WT + (size_t)e * IN_SZ * OUT_SZ);
    const float* Abase = A + (size_t)(off_e + rows0) * IN_SZ;

    const float* ap[2];
    int aw[2];
    #pragma unroll
    for (int i = 0; i < 2; ++i) {
        int idx = tid + THREADS * i;
        int row = idx >> 3, c4 = idx & 7;
        int gr = row <= maxr ? row : maxr;
        ap[i] = Abase + (size_t)gr * IN_SZ + c4 * 4;
        aw[i] = row * 64 + ((c4 * 8) ^ (((row >> 1) & 3) << 4));
    }
    const char* gB[2];
    #pragma unroll
    for (int i = 0; i < 2; ++i) {
        int c = w * 2 + i;
        int n = c * 16 + (l >> 2);
        int csrc = ((l & 3) * 16) ^ (((l >> 3) & 3) << 4);
        gB[i] = WTe + (size_t)(ct * BN + n) * (IN_SZ * 2) + csrc;
    }

    float4 ar[2];
    auto loadA = [&](int kt) {
        #pragma unroll
        for (int i = 0; i < 2; ++i)
            ar[i] = *(const float4*)(ap[i] + kt * BK);
    };
    auto writeA = [&](int buf) {
        #pragma unroll
        for (int i = 0; i < 2; ++i) {
            ushort4 pk;
            pk.x = f2bf(ar[i].x); pk.y = f2bf(ar[i].y);
            pk.z = f2bf(ar[i].z); pk.w = f2bf(ar[i].w);
            *(ushort4*)((char*)&lsA[buf][0] + aw[i]) = pk;
        }
    };
    auto stageB = [&](int buf, int kt) {
        #pragma unroll
        for (int i = 0; i < 2; ++i)
            GLOAD_LDS16(gB[i] + kt * 64, &lsB[buf][(w * 2 + i) * 512]);
    };

    int wm = (w >> 2) * 64, wn = (w & 3) * 64;
    int lrow = l & 15;
    int cb = ((l >> 4) * 16) ^ (((l >> 1) & 3) << 4);

    f32x4 acc[4][4] = {};

    loadA(0); stageB(0, 0);
    writeA(0);
    __syncthreads();

    #pragma unroll
    for (int j = 0; j < JT; ++j) {
        int cur = j & 1;
        if (j + 1 < JT) {
            loadA(j + 1);
            stageB(cur ^ 1, j + 1);
        }
        {
            const char* pA = (const char*)&lsA[cur][0];
            const char* pB = (const char*)&lsB[cur][0];
            short8 af[4];
            #pragma unroll
            for (int m = 0; m < 4; ++m)
                af[m] = *(const short8*)(pA + (wm + m * 16 + lrow) * 64 + cb);
            __builtin_amdgcn_s_setprio(1);
            #pragma unroll
            for (int n = 0; n < 4; ++n) {
                short8 bf = *(const short8*)(pB + (wn + n * 16 + lrow) * 64 + cb);
                #pragma unroll
                for (int m = 0; m < 4; ++m)
                    acc[m][n] = __builtin_amdgcn_mfma_f32_16x16x32_bf16(
                        af[m], bf, acc[m][n], 0, 0, 0);
            }
            __builtin_amdgcn_s_setprio(0);
        }
        if (j + 1 < JT)
            writeA(cur ^ 1);
        if (j < JT - 1)
            __syncthreads();
    }

    float* outb = out + (size_t)(off_e + rows0) * OUT_SZ + ct * BN + wn;
    #pragma unroll
    for (int m = 0; m < 4; ++m) {
        #pragma unroll
        for (int j = 0; j < 4; ++j) {
            int rl = wm + m * 16 + (l >> 4) * 4 + j;
            if (rl < rows_rem) {
                float* po = outb + (size_t)rl * OUT_SZ + lrow;
                #pragma unroll
                for (int n = 0; n < 4; ++n)
                    po[n * 16] = acc[m][n][j];
            }
        }
    }
}

extern "C" void kernel_launch(void* const* d_in, const int* in_sizes, int n_in,
                              void* d_out, int out_size, void* d_ws, size_t ws_size,
                              hipStream_t stream) {
    const float* A      = (const float*)d_in[0];
    const int* sizes    = (const int*)d_in[1];
    const float* W      = (const float*)d_in[2];
    float* out          = (float*)d_out;

    const size_t WT_BYTES  = (size_t)E_NUM * IN_SZ * OUT_SZ * 2;  // 32 MB
    const size_t ABF_OFF   = WT_BYTES + 65536;                    // 64K-aligned
    const size_t ABF_BYTES = (size_t)ATOT * 2;                    // 128 MB

    unsigned short* WT  = (unsigned short*)d_ws;
    int* offs           = (int*)((char*)d_ws + WT_BYTES);

    offsets_kernel<<<1, E_NUM, 0, stream>>>(sizes, offs);
    prep_wt<<<dim3(IN_SZ / 32, OUT_SZ / 32, E_NUM), 256, 0, stream>>>(W, WT);

    if (ws_size >= ABF_OFF + ABF_BYTES) {
        unsigned short* Abf = (unsigned short*)((char*)d_ws + ABF_OFF);
        prep_a<<<4096, 256, 0, stream>>>(A, Abf);
        gemm_moe_dma<<<NWG, THREADS, 0, stream>>>(Abf, sizes, WT, offs, out);
    } else {
        gemm_moe_reg<<<NWG, THREADS, 0, stream>>>(A, sizes, WT, offs, out);
    }
}

// Round 14
// 186.837 us; speedup vs baseline: 1.3024x; 1.3024x over previous
//
#include <hip/hip_runtime.h>
#include <hip/hip_bf16.h>

#define E_NUM 64
#define IN_SZ 512
#define OUT_SZ 512
#define N_TOK 131072
#define CAP 3072

#define BM 128
#define BN 256
#define BK 32
#define THREADS 256
#define RT_MAX 24   // CAP/BM
#define CT_NUM 2    // OUT/BN
#define JT 16       // IN_SZ/BK

typedef __attribute__((ext_vector_type(8))) short short8;
typedef __attribute__((ext_vector_type(4))) float f32x4;
typedef __attribute__((ext_vector_type(4))) unsigned int u32x4;

__device__ inline unsigned short f2bf(float f) {
    unsigned int u = __float_as_uint(f);
    unsigned int r = (u + 0x7FFF + ((u >> 16) & 1)) >> 16;
    return (unsigned short)r;
}

// packed fp32x2 -> bf16x2 (RNE), single HW instr on gfx950
__device__ inline unsigned int cvtpk(float a, float b) {
    unsigned int r;
    asm("v_cvt_pk_bf16_f32 %0, %1, %2" : "=v"(r) : "v"(a), "v"(b));
    return r;
}

#define GLOAD_LDS16(g, l)                                                     \
    __builtin_amdgcn_global_load_lds(                                         \
        (const __attribute__((address_space(1))) void*)(g),                   \
        (__attribute__((address_space(3))) void*)(l), 16, 0, 0)

// ---------------- kernel 1: exclusive prefix sum of expert sizes ----------
__global__ void offsets_kernel(const int* __restrict__ sizes, int* __restrict__ offs) {
    int e = threadIdx.x;
    int s = 0;
    for (int i = 0; i < e; ++i) s += sizes[i];
    offs[e] = s;
}

// ---------------- kernel 2: W [E][K][N] f32 -> WT [E][N][K] bf16 ----------
__global__ __launch_bounds__(256) void prep_wt(const float* __restrict__ W,
                                               unsigned short* __restrict__ WT) {
    __shared__ float t[32][33];
    int k0 = blockIdx.x * 32, n0 = blockIdx.y * 32, e = blockIdx.z;
    const float* We = W + (size_t)e * IN_SZ * OUT_SZ;
    int tid = threadIdx.x;
    int r = tid >> 3, c4 = (tid & 7) * 4;
    float4 v = *(const float4*)(We + (size_t)(k0 + r) * OUT_SZ + n0 + c4);
    t[r][c4 + 0] = v.x; t[r][c4 + 1] = v.y; t[r][c4 + 2] = v.z; t[r][c4 + 3] = v.w;
    __syncthreads();
    ushort4 o;
    o.x = f2bf(t[c4 + 0][r]);
    o.y = f2bf(t[c4 + 1][r]);
    o.z = f2bf(t[c4 + 2][r]);
    o.w = f2bf(t[c4 + 3][r]);
    unsigned short* O = WT + (size_t)e * IN_SZ * OUT_SZ + (size_t)(n0 + r) * IN_SZ + k0 + c4;
    *(ushort4*)O = o;
}

// ---------------- kernel 3: all-DMA grouped GEMM (best measured) ----------
// A staged as RAW FP32 via global_load_lds; fp32->bf16 at fragment-read
// (16 v_cvt_pk_bf16_f32/iter). B staged bf16. A = 3 bufs staged 2 ahead,
// B = 2 bufs staged 1 ahead. One barrier + one counted vmcnt per iter;
// end of iter j drains all but stageA(j+2) -> vmcnt(4).
__global__ __launch_bounds__(THREADS, 2) void gemm_moe(
    const float* __restrict__ A, const int* __restrict__ sizes,
    const unsigned short* __restrict__ WT, const int* __restrict__ offs,
    float* __restrict__ out)
{
    // bijective XCD swizzle: 3072 blocks, 384 per XCD chunk
    int b0 = blockIdx.x;
    int wg = (b0 & 7) * (E_NUM * RT_MAX * CT_NUM / 8) + (b0 >> 3);
    int ct = wg & (CT_NUM - 1);
    int rt = (wg >> 1) % RT_MAX;
    int e  = wg / (RT_MAX * CT_NUM);

    int size_e = sizes[e];
    int rows0 = rt * BM;
    if (rows0 >= size_e) return;
    int off_e = offs[e];
    int rows_rem = size_e - rows0;                      // >= 1
    int maxr = (rows_rem < BM ? rows_rem : BM) - 1;

    __shared__ float lsA[3][BM * BK];            // 3 x 16 KB (fp32)
    __shared__ unsigned short lsB[2][BN * BK];   // 2 x 16 KB  -> 80 KB total

    int tid = threadIdx.x, l = tid & 63, w = tid >> 6;
    const char* WTe = (const char*)(WT + (size_t)e * IN_SZ * OUT_SZ);
    const char* Abase = (const char*)(A + (size_t)(off_e + rows0) * IN_SZ);

    const char* gA[4];
    #pragma unroll
    for (int i = 0; i < 4; ++i) {
        int row = (w * 4 + i) * 8 + (l >> 3);        // LDS row 0..127
        int gr = row <= maxr ? row : maxr;           // clamped global row
        gA[i] = Abase + (size_t)gr * (IN_SZ * 4) + (((l & 7) ^ (row & 7)) * 16);
    }
    const char* gB[4];
    #pragma unroll
    for (int i = 0; i < 4; ++i) {
        int c = w * 4 + i;
        int n = c * 16 + (l >> 2);
        int csrc = ((l & 3) * 16) ^ (((l >> 3) & 3) << 4);
        gB[i] = WTe + (size_t)(ct * BN + n) * (IN_SZ * 2) + csrc;
    }

    auto stageA = [&](int buf, int kt) {
        #pragma unroll
        for (int i = 0; i < 4; ++i)
            GLOAD_LDS16(gA[i] + kt * 128, &lsA[buf][(w * 4 + i) * 256]);
    };
    auto stageB = [&](int buf, int kt) {
        #pragma unroll
        for (int i = 0; i < 4; ++i)
            GLOAD_LDS16(gB[i] + kt * 64, &lsB[buf][(w * 4 + i) * 512]);
    };

    int wm = (w >> 1) * 64, wn = (w & 1) * 128;
    int lrow = l & 15, kq = l >> 4;
    int abm[4];
    #pragma unroll
    for (int m = 0; m < 4; ++m) abm[m] = (wm + m * 16 + lrow) * 128;
    int as0 = ((kq * 2 + 0) ^ (lrow & 7)) * 16;
    int as1 = ((kq * 2 + 1) ^ (lrow & 7)) * 16;
    int cb = (kq * 16) ^ (((lrow >> 1) & 3) << 4);

    f32x4 acc[4][8] = {};

    #define FRAGS_AND_MFMA(bufA, bufB)                                        \
        {                                                                     \
            const char* pA = (const char*)&lsA[bufA][0];                      \
            const char* pB = (const char*)&lsB[bufB][0];                      \
            f32x4 av[4][2];                                                   \
            _Pragma("unroll")                                                 \
            for (int m = 0; m < 4; ++m) {                                     \
                av[m][0] = *(const f32x4*)(pA + abm[m] + as0);                \
                av[m][1] = *(const f32x4*)(pA + abm[m] + as1);                \
            }                                                                 \
            short8 bfr[8];                                                    \
            _Pragma("unroll")                                                 \
            for (int n = 0; n < 8; ++n)                                       \
                bfr[n] = *(const short8*)(pB + (wn + n * 16 + lrow) * 64 + cb);\
            asm volatile("s_waitcnt lgkmcnt(0)" ::: "memory");                \
            __builtin_amdgcn_sched_barrier(0);                                \
            short8 af[4];                                                     \
            _Pragma("unroll")                                                 \
            for (int m = 0; m < 4; ++m) {                                     \
                u32x4 au;                                                     \
                au[0] = cvtpk(av[m][0][0], av[m][0][1]);                      \
                au[1] = cvtpk(av[m][0][2], av[m][0][3]);                      \
                au[2] = cvtpk(av[m][1][0], av[m][1][1]);                      \
                au[3] = cvtpk(av[m][1][2], av[m][1][3]);                      \
                af[m] = __builtin_bit_cast(short8, au);                       \
            }                                                                 \
            __builtin_amdgcn_s_setprio(1);                                    \
            _Pragma("unroll")                                                 \
            for (int m = 0; m < 4; ++m)                                       \
                _Pragma("unroll")                                             \
                for (int n = 0; n < 8; ++n)                                   \
                    acc[m][n] = __builtin_amdgcn_mfma_f32_16x16x32_bf16(      \
                        af[m], bfr[n], acc[m][n], 0, 0, 0);                   \
            __builtin_amdgcn_s_setprio(0);                                    \
        }

    // ---- prologue: A0,B0,A1 staged; drain A0+B0, keep A1 in flight ----
    stageA(0, 0); stageB(0, 0);
    stageA(1, 1);
    asm volatile("s_waitcnt vmcnt(4)" ::: "memory");
    __builtin_amdgcn_sched_barrier(0);
    __builtin_amdgcn_s_barrier();
    __builtin_amdgcn_sched_barrier(0);

    #pragma unroll
    for (int j = 0; j < JT; ++j) {
        if (j + 1 < JT) stageB((j + 1) & 1, j + 1);
        FRAGS_AND_MFMA(j % 3, j & 1);
        if (j + 2 < JT) stageA((j + 2) % 3, j + 2);
        if (j < JT - 1) {
            if (j + 2 < JT) {
                asm volatile("s_waitcnt vmcnt(4)" ::: "memory");
            } else {
                asm volatile("s_waitcnt vmcnt(0)" ::: "memory");
            }
            __builtin_amdgcn_sched_barrier(0);
            __builtin_amdgcn_s_barrier();
            __builtin_amdgcn_sched_barrier(0);
        }
    }

    // epilogue: C/D layout col = lane&15, row = (lane>>4)*4 + reg
    float* outb = out + (size_t)(off_e + rows0) * OUT_SZ + ct * BN + wn;
    #pragma unroll
    for (int m = 0; m < 4; ++m) {
        #pragma unroll
        for (int j = 0; j < 4; ++j) {
            int rl = wm + m * 16 + kq * 4 + j;
            if (rl < rows_rem) {
                float* po = outb + (size_t)rl * OUT_SZ + lrow;
                #pragma unroll
                for (int n = 0; n < 8; ++n)
                    po[n * 16] = acc[m][n][j];
            }
        }
    }
}

extern "C" void kernel_launch(void* const* d_in, const int* in_sizes, int n_in,
                              void* d_out, int out_size, void* d_ws, size_t ws_size,
                              hipStream_t stream) {
    const float* A      = (const float*)d_in[0];
    const int* sizes    = (const int*)d_in[1];
    const float* W      = (const float*)d_in[2];
    float* out          = (float*)d_out;

    unsigned short* WT  = (unsigned short*)d_ws;                       // 32 MB
    int* offs           = (int*)((char*)d_ws + (size_t)E_NUM * IN_SZ * OUT_SZ * 2);

    offsets_kernel<<<1, E_NUM, 0, stream>>>(sizes, offs);
    prep_wt<<<dim3(IN_SZ / 32, OUT_SZ / 32, E_NUM), 256, 0, stream>>>(W, WT);
    gemm_moe<<<E_NUM * RT_MAX * CT_NUM, THREADS, 0, stream>>>(A, sizes, WT, offs, out);
}

// Round 15
// 184.620 us; speedup vs baseline: 1.3180x; 1.0120x over previous
//
#include <hip/hip_runtime.h>
#include <hip/hip_bf16.h>

#define E_NUM 64
#define IN_SZ 512
#define OUT_SZ 512
#define N_TOK 131072
#define CAP 3072

#define BM 256
#define BN 256
#define BK 64
#define THREADS 512
#define RT_MAX 12   // CAP/BM
#define CT_NUM 2    // OUT/BN
#define JT 8        // IN_SZ/BK
#define NWG (E_NUM * RT_MAX * CT_NUM)   // 1536

typedef __attribute__((ext_vector_type(8))) short short8;
typedef __attribute__((ext_vector_type(4))) float f32x4;

__device__ inline unsigned short f2bf(float f) {
    unsigned int u = __float_as_uint(f);
    unsigned int r = (u + 0x7FFF + ((u >> 16) & 1)) >> 16;
    return (unsigned short)r;
}

// packed fp32x2 -> bf16x2 (RNE), single HW instr on gfx950
__device__ inline unsigned int cvtpk(float a, float b) {
    unsigned int r;
    asm("v_cvt_pk_bf16_f32 %0, %1, %2" : "=v"(r) : "v"(a), "v"(b));
    return r;
}

#define GLOAD_LDS16(g, l)                                                     \
    __builtin_amdgcn_global_load_lds(                                         \
        (const __attribute__((address_space(1))) void*)(g),                   \
        (__attribute__((address_space(3))) void*)(l), 16, 0, 0)

// ---------------- kernel 1: exclusive prefix sum of expert sizes ----------
__global__ void offsets_kernel(const int* __restrict__ sizes, int* __restrict__ offs) {
    int e = threadIdx.x;
    int s = 0;
    for (int i = 0; i < e; ++i) s += sizes[i];
    offs[e] = s;
}

// ---------------- kernel 2: W [E][K][N] f32 -> WT [E][N][K] bf16 ----------
__global__ __launch_bounds__(256) void prep_wt(const float* __restrict__ W,
                                               unsigned short* __restrict__ WT) {
    __shared__ float t[32][33];
    int k0 = blockIdx.x * 32, n0 = blockIdx.y * 32, e = blockIdx.z;
    const float* We = W + (size_t)e * IN_SZ * OUT_SZ;
    int tid = threadIdx.x;
    int r = tid >> 3, c4 = (tid & 7) * 4;
    float4 v = *(const float4*)(We + (size_t)(k0 + r) * OUT_SZ + n0 + c4);
    t[r][c4 + 0] = v.x; t[r][c4 + 1] = v.y; t[r][c4 + 2] = v.z; t[r][c4 + 3] = v.w;
    __syncthreads();
    ushort4 o;
    o.x = f2bf(t[c4 + 0][r]);
    o.y = f2bf(t[c4 + 1][r]);
    o.z = f2bf(t[c4 + 2][r]);
    o.w = f2bf(t[c4 + 3][r]);
    unsigned short* O = WT + (size_t)e * IN_SZ * OUT_SZ + (size_t)(n0 + r) * IN_SZ + k0 + c4;
    *(ushort4*)O = o;
}

// ---------------- kernel 3: 256x256 BK=64 2-phase grouped GEMM ------------
// m248-V1 analog (grouped 2ph 256^2, 655-666 TF refcheck'd @K=1024).
// 8 waves (2M x 4N), wave tile 128x64, acc[8][4]=128 regs; lb(512,2).
// LDS 128 KB: A bf16 [256][64] 32K + B 32K, double-buffered; 1 block/CU.
// A: reg-staged fp32 (8 dwordx4/thread, issued a full compute early) ->
//    16 cvtpk -> 4 ds_write_b128. B: 4 global_load_lds(16B)/wave.
// Swizzle (128 B rows = 8 x 16B slots): data chunk c lives at slot
// s = c ^ (row&7). Uniform 8 lanes/bank-group on b128 reads (= HW floor).
// B involution via pre-swizzled global source (rule #21).
__global__ __launch_bounds__(THREADS, 2) void gemm_moe(
    const float* __restrict__ A, const int* __restrict__ sizes,
    const unsigned short* __restrict__ WT, const int* __restrict__ offs,
    float* __restrict__ out)
{
    // bijective XCD swizzle: 1536 blocks, 192 per XCD chunk
    int b0 = blockIdx.x;
    int wg = (b0 & 7) * (NWG / 8) + (b0 >> 3);
    int ct = wg & (CT_NUM - 1);
    int rt = (wg >> 1) % RT_MAX;
    int e  = wg / (RT_MAX * CT_NUM);

    int size_e = sizes[e];
    int rows0 = rt * BM;
    if (rows0 >= size_e) return;
    int off_e = offs[e];
    int rows_rem = size_e - rows0;                      // >= 1
    int maxr = (rows_rem < BM ? rows_rem : BM) - 1;

    __shared__ unsigned short lsA[2][BM * BK];   // 2 x 32 KB
    __shared__ unsigned short lsB[2][BN * BK];   // 2 x 32 KB -> 128 KB

    int tid = threadIdx.x, l = tid & 63, w = tid >> 6;   // w in 0..7
    const char* WTe = (const char*)(WT + (size_t)e * IN_SZ * OUT_SZ);
    const float* Abase = A + (size_t)(off_e + rows0) * IN_SZ;

    // ---- A staging geometry: 2048 16B-units; thread owns u = tid + 512*jj.
    // unit u -> LDS row u>>3, slot u&7; holds global k-chunk c = s^(row&7).
    int aoff[4];            // fp32 element offset of the unit's global data
    #pragma unroll
    for (int jj = 0; jj < 4; ++jj) {
        int u = tid + THREADS * jj;
        int row = u >> 3, s = u & 7;
        int c = s ^ (row & 7);
        int gr = row <= maxr ? row : maxr;
        aoff[jj] = gr * IN_SZ + c * 8;
    }
    // ---- B staging: 4 gload calls/wave; call i dest units (w*4+i)*64 + l.
    int boff[4];            // byte offset within WTe (minus kt term)
    #pragma unroll
    for (int i = 0; i < 4; ++i) {
        int unit = (w * 4 + i) * 64 + l;
        int row = unit >> 3, s = unit & 7;
        int c = s ^ (row & 7);
        boff[i] = (ct * BN + row) * (IN_SZ * 2) + c * 16;
    }

    f32x4 ar[8];            // single in-flight A register set (32 VGPR)

    auto loadA = [&](int kt) {
        #pragma unroll
        for (int jj = 0; jj < 4; ++jj) {
            ar[2 * jj]     = *(const f32x4*)(Abase + aoff[jj] + kt * BK);
            ar[2 * jj + 1] = *(const f32x4*)(Abase + aoff[jj] + kt * BK + 4);
        }
    };
    auto writeA = [&](int buf) {
        #pragma unroll
        for (int jj = 0; jj < 4; ++jj) {
            unsigned int p0 = cvtpk(ar[2 * jj][0], ar[2 * jj][1]);
            unsigned int p1 = cvtpk(ar[2 * jj][2], ar[2 * jj][3]);
            unsigned int p2 = cvtpk(ar[2 * jj + 1][0], ar[2 * jj + 1][1]);
            unsigned int p3 = cvtpk(ar[2 * jj + 1][2], ar[2 * jj + 1][3]);
            uint4 pk = make_uint4(p0, p1, p2, p3);
            *(uint4*)((char*)&lsA[buf][0] + (tid + THREADS * jj) * 16) = pk;
        }
    };
    auto stageB = [&](int buf, int kt) {
        #pragma unroll
        for (int i = 0; i < 4; ++i)
            GLOAD_LDS16(WTe + boff[i] + kt * 128, &lsB[buf][(w * 4 + i) * 512]);
    };

    int wm = (w >> 2) * 128, wn = (w & 3) * 64;  // 2M x 4N, wave tile 128x64
    int lrow = l & 15, kq = l >> 4;
    int abm[8], bbn[4];
    #pragma unroll
    for (int mm = 0; mm < 8; ++mm) abm[mm] = (wm + mm * 16 + lrow) * 128;
    #pragma unroll
    for (int nn = 0; nn < 4; ++nn) bbn[nn] = (wn + nn * 16 + lrow) * 128;
    int sk0 = ((0 * 4 + kq) ^ (lrow & 7)) * 16;   // ks=0 slot byte
    int sk1 = ((1 * 4 + kq) ^ (lrow & 7)) * 16;   // ks=1 slot byte

    f32x4 acc[8][4] = {};

    // ---- prologue: tile 0 staged ----
    loadA(0); stageB(0, 0);
    writeA(0);                 // compiler waits A0 loads only
    __syncthreads();           // drains B0 DMA + A0 ds_writes

    // ---- main loop: 8 iterations, one barrier each ----
    #pragma unroll
    for (int j = 0; j < JT; ++j) {
        int cur = j & 1;
        if (j + 1 < JT) {
            loadA(j + 1);            // fp32 A -> regs (MFMA-phase of slack)
            stageB(cur ^ 1, j + 1);  // B DMA -> other buffer
        }
        {
            const char* pA = (const char*)&lsA[cur][0];
            const char* pB = (const char*)&lsB[cur][0];
            __builtin_amdgcn_s_setprio(1);
            #pragma unroll
            for (int ks = 0; ks < 2; ++ks) {
                int sk = ks ? sk1 : sk0;
                short8 bfr[4];
                #pragma unroll
                for (int nn = 0; nn < 4; ++nn)
                    bfr[nn] = *(const short8*)(pB + bbn[nn] + sk);
                #pragma unroll
                for (int mm = 0; mm < 8; ++mm) {
                    short8 af = *(const short8*)(pA + abm[mm] + sk);
                    #pragma unroll
                    for (int nn = 0; nn < 4; ++nn)
                        acc[mm][nn] = __builtin_amdgcn_mfma_f32_16x16x32_bf16(
                            af, bfr[nn], acc[mm][nn], 0, 0, 0);
                }
            }
            __builtin_amdgcn_s_setprio(0);
        }
        if (j + 1 < JT)
            writeA(cur ^ 1);         // cvt+ds_write; loads had full MFMA slack
        if (j < JT - 1)
            __syncthreads();
    }

    // epilogue: C/D layout col = lane&15, row = (lane>>4)*4 + reg
    float* outb = out + (size_t)(off_e + rows0) * OUT_SZ + ct * BN + wn;
    #pragma unroll
    for (int mm = 0; mm < 8; ++mm) {
        #pragma unroll
        for (int jj = 0; jj < 4; ++jj) {
            int rl = wm + mm * 16 + kq * 4 + jj;
            if (rl < rows_rem) {
                float* po = outb + (size_t)rl * OUT_SZ + lrow;
                #pragma unroll
                for (int nn = 0; nn < 4; ++nn)
                    po[nn * 16] = acc[mm][nn][jj];
            }
        }
    }
}

extern "C" void kernel_launch(void* const* d_in, const int* in_sizes, int n_in,
                              void* d_out, int out_size, void* d_ws, size_t ws_size,
                              hipStream_t stream) {
    const float* A      = (const float*)d_in[0];
    const int* sizes    = (const int*)d_in[1];
    const float* W      = (const float*)d_in[2];
    float* out          = (float*)d_out;

    unsigned short* WT  = (unsigned short*)d_ws;                       // 32 MB
    int* offs           = (int*)((char*)d_ws + (size_t)E_NUM * IN_SZ * OUT_SZ * 2);

    offsets_kernel<<<1, E_NUM, 0, stream>>>(sizes, offs);
    prep_wt<<<dim3(IN_SZ / 32, OUT_SZ / 32, E_NUM), 256, 0, stream>>>(W, WT);
    gemm_moe<<<NWG, THREADS, 0, stream>>>(A, sizes, WT, offs, out);
}